// Round 2
// baseline (102.906 us; speedup 1.0000x reference)
//
#include <hip/hip_runtime.h>
#include <math.h>

#define BB 16
#define LL 2048
#define DD 256
#define NPOS 126
#define NSEG 127                 // chunk_counts bins = NPOS + 1
#define MS 1152                  // max segments per utterance
#define POS_MAX (24 + 16 * (NPOS - 1))   // 2024
#define SB 72                    // sub-blocks per batch in fused kernel
#define SLOTS 16                 // MS / SB segment slots per block

// ws layout: w : BB*LL floats @ byte 0

// ---------------- Kernel 1: w[b,t] = sigmoid(x[b,t,:] . w_lin + b_lin) -------
// one wave per row; 64 lanes x float4 = 256 dims
__global__ __launch_bounds__(256) void k_proj(const float* __restrict__ xs,
                                              const float* __restrict__ w_lin,
                                              const float* __restrict__ b_lin,
                                              float* __restrict__ w) {
    int gtid = blockIdx.x * 256 + threadIdx.x;
    int row  = gtid >> 6;          // wave id == row, grid sized exactly
    int lane = threadIdx.x & 63;
    const float4 x4 = *(const float4*)(xs + (size_t)row * DD + lane * 4);
    const float4 wl = *(const float4*)(w_lin + lane * 4);
    float p = x4.x * wl.x + x4.y * wl.y + x4.z * wl.z + x4.w * wl.w;
    #pragma unroll
    for (int off = 32; off > 0; off >>= 1) p += __shfl_down(p, off, 64);
    if (lane == 0) {
        float x = p + b_lin[0];
        float s = (x >= 0.f) ? 1.f / (1.f + expf(-x))
                             : expf(x) / (1.f + expf(x));
        w[row] = s;
    }
}

// -------- Kernel 2 (fused): mask+scan in LDS, then segment mean + LayerNorm --
// grid = BB * SB blocks of 256. Each block recomputes its batch's mask/scan
// (cheap, 8 KB L2-hit) and then owns SLOTS consecutive segment slots.
__global__ __launch_bounds__(256) void k_fused(const float* __restrict__ xs,
                                               const float* __restrict__ w,
                                               const float* __restrict__ gamma,
                                               const float* __restrict__ beta,
                                               float* __restrict__ out,
                                               float* __restrict__ out_counts,
                                               float* __restrict__ out_cc) {
    int bx = blockIdx.x;
    int b  = bx / SB;
    int sb = bx - b * SB;
    int tid = threadIdx.x;
    int lane = tid & 63, wv = tid >> 6;

    __shared__ float sw[LL];
    __shared__ int   sstarts[MS];
    __shared__ int   scc[NSEG];
    __shared__ int   wave_tot[4];

    for (int i = tid; i < LL; i += 256) sw[i] = w[b * LL + i];
    if (sb == 0) for (int i = tid; i < NSEG; i += 256) scc[i] = 0;
    __syncthreads();

    // ---- mask bits: strict local minima (zero-pad boundaries) + forced ----
    int base_t = tid * 8;
    bool bits[8];
    int c = 0;
    #pragma unroll
    for (int j = 0; j < 8; ++j) {
        int t = base_t + j;
        float wd = sw[t];
        float pv = (t > 0)      ? sw[t - 1] : 0.f;
        float nx = (t < LL - 1) ? sw[t + 1] : 0.f;
        bool m = (wd < pv) && (wd < nx);
        if (t == 0) m = true;
        if (t >= 24 && t <= POS_MAX && ((t - 24) & 15) == 0) m = true;
        bits[j] = m;
        c += m ? 1 : 0;
    }

    // ---- block exclusive scan over per-thread counts (4 waves of 64) ----
    int inc = c;
    #pragma unroll
    for (int off = 1; off < 64; off <<= 1) {
        int v = __shfl_up(inc, off, 64);
        if (lane >= off) inc += v;
    }
    if (lane == 63) wave_tot[wv] = inc;
    __syncthreads();
    int wbase = 0;
    for (int i = 0; i < wv; ++i) wbase += wave_tot[i];
    int total = wave_tot[0] + wave_tot[1] + wave_tot[2] + wave_tot[3];
    int rank  = wbase + inc - c;

    #pragma unroll
    for (int j = 0; j < 8; ++j) {
        if (bits[j]) {
            int t = base_t + j;
            sstarts[rank] = t;
            ++rank;
            if (sb == 0) {
                int sid = (t < 24) ? 0 : min((t - 24) / 16 + 1, NSEG - 1);
                atomicAdd(&scc[sid], 1);
            }
        }
    }
    for (int i = total + tid; i < MS; i += 256) sstarts[i] = LL;
    __syncthreads();

    if (sb == 0) {
        if (tid == 0) out_counts[b] = (float)total;
        for (int i = tid; i < NSEG; i += 256) out_cc[b * NSEG + i] = (float)scc[i];
    }

    // ---- segment phase: SLOTS slots, interleaved across the 4 waves ----
    const float4 g  = *(const float4*)(gamma + lane * 4);
    const float4 bt = *(const float4*)(beta + lane * 4);
    #pragma unroll
    for (int j = 0; j < SLOTS / 4; ++j) {
        int k = sb * SLOTS + j * 4 + wv;
        float* orow = out + ((size_t)(b * MS + k)) * DD + lane * 4;
        if (k >= total) {        // padded slot -> zeros after LN
            *(float4*)orow = make_float4(0.f, 0.f, 0.f, 0.f);
            continue;
        }
        int start = sstarts[k];
        int end   = (k + 1 < total) ? min(sstarts[k + 1] + 2, LL) : LL;

        float4 acc = make_float4(0.f, 0.f, 0.f, 0.f);
        float den = 0.f;
        const float* xrow = xs + ((size_t)(b * LL + start)) * DD + lane * 4;
        for (int t = start; t < end; ++t, xrow += DD) {
            float wt = sw[t];                 // LDS broadcast, no global read
            float4 x4 = *(const float4*)xrow;
            acc.x += wt * x4.x; acc.y += wt * x4.y;
            acc.z += wt * x4.z; acc.w += wt * x4.w;
            den += wt;
        }
        float invd = 1.f / fmaxf(den, 1e-6f);
        float4 v = make_float4(acc.x * invd, acc.y * invd,
                               acc.z * invd, acc.w * invd);

        float s = v.x + v.y + v.z + v.w;
        #pragma unroll
        for (int off = 32; off > 0; off >>= 1) s += __shfl_down(s, off, 64);
        s = __shfl(s, 0, 64);
        float mu = s * (1.f / DD);
        float dx = v.x - mu, dy = v.y - mu, dz = v.z - mu, dw = v.w - mu;
        float q = dx * dx + dy * dy + dz * dz + dw * dw;
        #pragma unroll
        for (int off = 32; off > 0; off >>= 1) q += __shfl_down(q, off, 64);
        q = __shfl(q, 0, 64);
        float rstd = rsqrtf(q * (1.f / DD) + 1e-5f);

        float4 o;
        o.x = dx * rstd * g.x + bt.x;
        o.y = dy * rstd * g.y + bt.y;
        o.z = dz * rstd * g.z + bt.z;
        o.w = dw * rstd * g.w + bt.w;
        *(float4*)orow = o;
    }
}

extern "C" void kernel_launch(void* const* d_in, const int* in_sizes, int n_in,
                              void* d_out, int out_size, void* d_ws, size_t ws_size,
                              hipStream_t stream) {
    const float* xs    = (const float*)d_in[0];
    // d_in[1] = olens (unused by reference math)
    const float* w_lin = (const float*)d_in[2];
    const float* b_lin = (const float*)d_in[3];
    const float* gamma = (const float*)d_in[4];
    const float* beta  = (const float*)d_in[5];

    float* out       = (float*)d_out;                       // [B,MS,D]
    float* out_cnt   = out + (size_t)BB * MS * DD;          // [B] as f32
    float* out_cc    = out_cnt + BB;                        // [B,NSEG] as f32

    float* w         = (float*)d_ws;                        // [B,L]

    // K1: BB*LL rows, 1 wave each, 4 waves/block
    k_proj<<<(BB * LL) / 4, 256, 0, stream>>>(xs, w_lin, b_lin, w);
    // K2 fused: BB*SB blocks, each owns SLOTS segment slots
    k_fused<<<BB * SB, 256, 0, stream>>>(xs, w, gamma, beta,
                                         out, out_cnt, out_cc);
}

// Round 3
// 99.878 us; speedup vs baseline: 1.0303x; 1.0303x over previous
//
#include <hip/hip_runtime.h>
#include <math.h>

#define BB 16
#define LL 2048
#define DD 256
#define NPOS 126
#define NSEG 127                 // chunk_counts bins = NPOS + 1
#define MS 1152                  // max segments per utterance
#define POS_MAX (24 + 16 * (NPOS - 1))   // 2024
#define SB 72                    // sub-blocks per batch in fused kernel
#define SLOTS 16                 // MS / SB segment slots per block

// ws layout: w : BB*LL floats @ byte 0

// ---------------- Kernel 1: w[b,t] = sigmoid(x[b,t,:] . w_lin + b_lin) -------
// 2 rows per wave: two independent 1 KB loads in flight, one shared reduction
// schedule. grid = BB*LL/8 blocks of 256 (4 waves x 2 rows each).
__global__ __launch_bounds__(256) void k_proj(const float* __restrict__ xs,
                                              const float* __restrict__ w_lin,
                                              const float* __restrict__ b_lin,
                                              float* __restrict__ w) {
    int gtid = blockIdx.x * 256 + threadIdx.x;
    int wid  = gtid >> 6;          // wave id; rows 2*wid, 2*wid+1
    int lane = threadIdx.x & 63;
    size_t r0 = (size_t)wid * 2;
    const float4 x0 = *(const float4*)(xs + r0 * DD + lane * 4);
    const float4 x1 = *(const float4*)(xs + (r0 + 1) * DD + lane * 4);
    const float4 wl = *(const float4*)(w_lin + lane * 4);
    float p0 = x0.x * wl.x + x0.y * wl.y + x0.z * wl.z + x0.w * wl.w;
    float p1 = x1.x * wl.x + x1.y * wl.y + x1.z * wl.z + x1.w * wl.w;
    #pragma unroll
    for (int off = 32; off > 0; off >>= 1) {
        p0 += __shfl_down(p0, off, 64);
        p1 += __shfl_down(p1, off, 64);
    }
    if (lane == 0) {
        float bl = b_lin[0];
        float a0 = p0 + bl, a1 = p1 + bl;
        float s0 = (a0 >= 0.f) ? 1.f / (1.f + expf(-a0))
                               : expf(a0) / (1.f + expf(a0));
        float s1 = (a1 >= 0.f) ? 1.f / (1.f + expf(-a1))
                               : expf(a1) / (1.f + expf(a1));
        w[r0]     = s0;
        w[r0 + 1] = s1;
    }
}

// -------- Kernel 2 (fused): mask+scan in LDS, then segment mean + LayerNorm --
// grid = BB * SB blocks of 256. Each block recomputes its batch's mask/scan
// (cheap, 8 KB L2-hit) and then owns SLOTS consecutive segment slots.
__global__ __launch_bounds__(256) void k_fused(const float* __restrict__ xs,
                                               const float* __restrict__ w,
                                               const float* __restrict__ gamma,
                                               const float* __restrict__ beta,
                                               float* __restrict__ out,
                                               float* __restrict__ out_counts,
                                               float* __restrict__ out_cc) {
    int bx = blockIdx.x;
    int b  = bx / SB;
    int sb = bx - b * SB;
    int tid = threadIdx.x;
    int lane = tid & 63, wv = tid >> 6;

    __shared__ float sw[LL];
    __shared__ int   sstarts[MS];     // only [0,total) ever read
    __shared__ int   scc[NSEG];
    __shared__ int   wave_tot[4];

    for (int i = tid; i < LL; i += 256) sw[i] = w[b * LL + i];
    if (sb == 0) for (int i = tid; i < NSEG; i += 256) scc[i] = 0;
    __syncthreads();

    // ---- mask bits: strict local minima (zero-pad boundaries) + forced ----
    int base_t = tid * 8;
    bool bits[8];
    int c = 0;
    #pragma unroll
    for (int j = 0; j < 8; ++j) {
        int t = base_t + j;
        float wd = sw[t];
        float pv = (t > 0)      ? sw[t - 1] : 0.f;
        float nx = (t < LL - 1) ? sw[t + 1] : 0.f;
        bool m = (wd < pv) && (wd < nx);
        if (t == 0) m = true;
        if (t >= 24 && t <= POS_MAX && ((t - 24) & 15) == 0) m = true;
        bits[j] = m;
        c += m ? 1 : 0;
    }

    // ---- block exclusive scan over per-thread counts (4 waves of 64) ----
    int inc = c;
    #pragma unroll
    for (int off = 1; off < 64; off <<= 1) {
        int v = __shfl_up(inc, off, 64);
        if (lane >= off) inc += v;
    }
    if (lane == 63) wave_tot[wv] = inc;
    __syncthreads();
    int wbase = 0;
    for (int i = 0; i < wv; ++i) wbase += wave_tot[i];
    int total = wave_tot[0] + wave_tot[1] + wave_tot[2] + wave_tot[3];
    int rank  = wbase + inc - c;

    #pragma unroll
    for (int j = 0; j < 8; ++j) {
        if (bits[j]) {
            int t = base_t + j;
            sstarts[rank] = t;
            ++rank;
            if (sb == 0) {
                int sid = (t < 24) ? 0 : min((t - 24) / 16 + 1, NSEG - 1);
                atomicAdd(&scc[sid], 1);
            }
        }
    }
    __syncthreads();

    if (sb == 0) {
        if (tid == 0) out_counts[b] = (float)total;
        for (int i = tid; i < NSEG; i += 256) out_cc[b * NSEG + i] = (float)scc[i];
    }

    // ---- segment phase: SLOTS slots, interleaved across the 4 waves ----
    const float4 g  = *(const float4*)(gamma + lane * 4);
    const float4 bt = *(const float4*)(beta + lane * 4);
    #pragma unroll
    for (int j = 0; j < SLOTS / 4; ++j) {
        int k = sb * SLOTS + j * 4 + wv;
        float* orow = out + ((size_t)(b * MS + k)) * DD + lane * 4;
        if (k >= total) {        // padded slot -> zeros after LN
            *(float4*)orow = make_float4(0.f, 0.f, 0.f, 0.f);
            continue;
        }
        int start = sstarts[k];
        int end   = (k + 1 < total) ? min(sstarts[k + 1] + 2, LL) : LL;

        float4 acc = make_float4(0.f, 0.f, 0.f, 0.f);
        float den = 0.f;
        const float* xrow = xs + ((size_t)(b * LL + start)) * DD + lane * 4;
        for (int t = start; t < end; ++t, xrow += DD) {
            float wt = sw[t];                 // LDS broadcast, no global read
            float4 x4 = *(const float4*)xrow;
            acc.x += wt * x4.x; acc.y += wt * x4.y;
            acc.z += wt * x4.z; acc.w += wt * x4.w;
            den += wt;
        }
        float invd = 1.f / fmaxf(den, 1e-6f);
        float4 v = make_float4(acc.x * invd, acc.y * invd,
                               acc.z * invd, acc.w * invd);

        float s = v.x + v.y + v.z + v.w;
        #pragma unroll
        for (int off = 32; off > 0; off >>= 1) s += __shfl_down(s, off, 64);
        s = __shfl(s, 0, 64);
        float mu = s * (1.f / DD);
        float dx = v.x - mu, dy = v.y - mu, dz = v.z - mu, dw = v.w - mu;
        float q = dx * dx + dy * dy + dz * dz + dw * dw;
        #pragma unroll
        for (int off = 32; off > 0; off >>= 1) q += __shfl_down(q, off, 64);
        q = __shfl(q, 0, 64);
        float rstd = rsqrtf(q * (1.f / DD) + 1e-5f);

        float4 o;
        o.x = dx * rstd * g.x + bt.x;
        o.y = dy * rstd * g.y + bt.y;
        o.z = dz * rstd * g.z + bt.z;
        o.w = dw * rstd * g.w + bt.w;
        *(float4*)orow = o;
    }
}

extern "C" void kernel_launch(void* const* d_in, const int* in_sizes, int n_in,
                              void* d_out, int out_size, void* d_ws, size_t ws_size,
                              hipStream_t stream) {
    const float* xs    = (const float*)d_in[0];
    // d_in[1] = olens (unused by reference math)
    const float* w_lin = (const float*)d_in[2];
    const float* b_lin = (const float*)d_in[3];
    const float* gamma = (const float*)d_in[4];
    const float* beta  = (const float*)d_in[5];

    float* out       = (float*)d_out;                       // [B,MS,D]
    float* out_cnt   = out + (size_t)BB * MS * DD;          // [B] as f32
    float* out_cc    = out_cnt + BB;                        // [B,NSEG] as f32

    float* w         = (float*)d_ws;                        // [B,L]

    // K1: BB*LL rows, 2 rows per wave, 4 waves/block
    k_proj<<<(BB * LL) / 8, 256, 0, stream>>>(xs, w_lin, b_lin, w);
    // K2 fused: BB*SB blocks, each owns SLOTS segment slots
    k_fused<<<BB * SB, 256, 0, stream>>>(xs, w, gamma, beta,
                                         out, out_cnt, out_cc);
}